// Round 2
// 2556.926 us; speedup vs baseline: 1.3053x; 1.3053x over previous
//
#include <hip/hip_runtime.h>
#include <cmath>

constexpr int  Bn  = 32, Tn = 512, NIn = 128, Hn = 1024;
constexpr long long TH  = (long long)Tn * Hn;    // 524288
constexpr long long BTH = (long long)Bn * TH;    // 16777216
constexpr float DTc  = 0.042f;
constexpr float UDEC = 1.0f - 1.0f * 1.0f * DTc; // R*C*dt leak
constexpr float HARM = 512.0f;                   // n_hid * p
constexpr float SPIK = 512.0f;                   // n_hid - harmonic

// Per-b-group arrival counters, monotonic (64 blocks each bump once per step).
__device__ unsigned g_ctr[4 * 64];

__global__ void init_ctr() {
    if (threadIdx.x < 4)
        __hip_atomic_store(&g_ctr[threadIdx.x * 64], 0u,
                           __ATOMIC_RELAXED, __HIP_MEMORY_SCOPE_AGENT);
}

// ---------------------------------------------------------------------------
// pre[row, col] = x[row, :] @ x2h[:, col] + bias[col]  (unchanged, verified)
// ---------------------------------------------------------------------------
__global__ __launch_bounds__(256) void pre_gemm(const float* __restrict__ x,
                                                const float* __restrict__ x2h,
                                                const float* __restrict__ bias,
                                                float* __restrict__ pre) {
    __shared__ float xs[64 * 128];   // [row][k]
    __shared__ float ws[128 * 64];   // [k][col]
    const int tid = threadIdx.x;
    const int rb  = blockIdx.y * 64;
    const int cb  = blockIdx.x * 64;

#pragma unroll
    for (int i = 0; i < 8; ++i) {
        int idx = i * 1024 + tid * 4;
        int r = idx >> 7, k = idx & 127;
        *(float4*)(&xs[r * 128 + k]) =
            *(const float4*)(&x[(long long)(rb + r) * NIn + k]);
    }
#pragma unroll
    for (int i = 0; i < 8; ++i) {
        int idx = i * 1024 + tid * 4;
        int k = idx >> 6, c = idx & 63;
        *(float4*)(&ws[k * 64 + c]) =
            *(const float4*)(&x2h[(long long)k * Hn + cb + c]);
    }
    __syncthreads();

    const int tx = tid & 15, ty = tid >> 4;
    const int r0 = ty * 4, c0 = tx * 4;
    float acc[4][4] = {};
#pragma unroll 4
    for (int k = 0; k < 128; ++k) {
        float4 bv = *(const float4*)(&ws[k * 64 + c0]);
        float a0 = xs[(r0 + 0) * 128 + k];
        float a1 = xs[(r0 + 1) * 128 + k];
        float a2 = xs[(r0 + 2) * 128 + k];
        float a3 = xs[(r0 + 3) * 128 + k];
        acc[0][0] += a0 * bv.x; acc[0][1] += a0 * bv.y; acc[0][2] += a0 * bv.z; acc[0][3] += a0 * bv.w;
        acc[1][0] += a1 * bv.x; acc[1][1] += a1 * bv.y; acc[1][2] += a1 * bv.z; acc[1][3] += a1 * bv.w;
        acc[2][0] += a2 * bv.x; acc[2][1] += a2 * bv.y; acc[2][2] += a2 * bv.z; acc[2][3] += a2 * bv.w;
        acc[3][0] += a3 * bv.x; acc[3][1] += a3 * bv.y; acc[3][2] += a3 * bv.z; acc[3][3] += a3 * bv.w;
    }
    float4 bb = *(const float4*)(&bias[cb + c0]);
#pragma unroll
    for (int i = 0; i < 4; ++i) {
        float4 o;
        o.x = acc[i][0] + bb.x; o.y = acc[i][1] + bb.y;
        o.z = acc[i][2] + bb.z; o.w = acc[i][3] + bb.w;
        *(float4*)(&pre[(long long)(rb + r0 + i) * Hn + cb + c0]) = o;
    }
}

// ---------------------------------------------------------------------------
// Persistent recurrence kernel. 256 blocks = 4 b-groups x 64 h-groups.
// R4 change (resubmit): register-tiled dot. Each thread computes a 4x4
// (batch x col) output tile over a lane-interleaved K=32 chunk (K-split 32).
// LDS-delivered bytes for the dot drop 4x (1 MB -> 256 KB per block per
// step); ds_read_b128 count drops 256 -> 64 per thread. K-partials are
// combined via a stride-33 LDS scratch aliased onto the (dead-at-that-point)
// hyl staging region.
// ---------------------------------------------------------------------------
__global__ __launch_bounds__(256, 1) void ron_loop(const float* __restrict__ h2h,
                                                   const float* __restrict__ gam,
                                                   const float* __restrict__ eps,
                                                   float* __restrict__ out) {
    extern __shared__ float sm[];
    float* hyl  = sm;                // 8 * 1028 floats (staging)
    float* wt   = sm + 8 * 1028;     // 16 * 1028 floats (weights, resident)
    float* part = sm;                // alias hyl: 128 outputs * 33 floats

    const int tid = threadIdx.x;
    const int bx  = blockIdx.x;
    const int hg  = bx & 63;         // 64 h-groups
    const int bg  = bx >> 6;         // 4 b-groups
    const int c0  = hg * 16;
    const int b0  = bg * 8;
    unsigned* ctr = &g_ctr[bg * 64];

    float* hy_o = out;
    float* hz_o = out + BTH;
    float* u_o  = out + 2 * BTH;     // holds pre until overwritten by u
    float* sp_o = out + 3 * BTH;

    // Stage transposed h2h slice (once). Coalesced global reads.
    for (int idx = tid; idx < 16 * 1024; idx += 256) {
        int cc2 = idx & 15, k = idx >> 4;
        wt[cc2 * 1028 + k] = h2h[(long long)k * Hn + c0 + cc2];
    }

    // ---- dot decomposition: 8 tiles (2 batch-quads x 4 col-quads) x 32 K-chunks
    const int ks   = tid & 31;       // K-split lane: float4 index ks + 32*m
    const int tile = tid >> 5;       // 0..7
    const int tb   = tile >> 2;      // 0..1  batch quad (rows tb*4 .. tb*4+3)
    const int tc   = tile & 3;       // 0..3  col quad  (cols tc*4 .. tc*4+3)
    const float* hp0 = hyl + (tb * 4 + 0) * 1028 + ks * 4;
    const float* hp1 = hp0 + 1028;
    const float* hp2 = hp0 + 2 * 1028;
    const float* hp3 = hp0 + 3 * 1028;
    const float* wp0 = wt + (tc * 4 + 0) * 1028 + ks * 4;
    const float* wp1 = wp0 + 1028;
    const float* wp2 = wp0 + 2 * 1028;
    const float* wp3 = wp0 + 3 * 1028;
    float* pw = part + (tb * 64 + tc * 4) * 33 + ks;   // o*33 + ks

    // ---- update-phase identity (threads 0..127 own one (b,h) output) ----
    const int r  = tid & 127;
    const int cc = r & 15;
    const int bb = r >> 4;
    const int b  = b0 + bb;
    const int h  = c0 + cc;
    const float g = gam[h];
    const float e = eps[h];
    float hy = 0.0f, hz = 0.0f, u = 0.0f;

#define D4(dst, hv, wv)                                         \
    dst = fmaf(hv.x, wv.x, dst); dst = fmaf(hv.y, wv.y, dst);   \
    dst = fmaf(hv.z, wv.z, dst); dst = fmaf(hv.w, wv.w, dst)

    for (int t = 0; t < Tn; ++t) {
        // prefetch pre (HBM, ~900 cyc) first: retires during staging+dot
        float pre_v = 0.0f;
        if (tid < 128)
            pre_v = u_o[(long long)b * TH + (long long)t * Hn + h];

        float acc = 0.0f;
        if (t > 0) {
            // ---- stage previous hy rows: 32 L3 loads ALL in flight ----
            const long long base = (long long)b0 * TH + (long long)(t - 1) * Hn + tid;
            float v[32];
#pragma unroll
            for (int i = 0; i < 32; ++i) {
                v[i] = __hip_atomic_load(
                    &hy_o[base + (long long)(i >> 2) * TH + (i & 3) * 256],
                    __ATOMIC_RELAXED, __HIP_MEMORY_SCOPE_AGENT);
            }
#pragma unroll
            for (int i = 0; i < 32; ++i)
                hyl[(i >> 2) * 1028 + (i & 3) * 256 + tid] = v[i];
            __syncthreads();

            // ---- register-tiled dot: 4x4 outputs, K=32 (lane-interleaved) ----
            float a00 = 0.f, a01 = 0.f, a02 = 0.f, a03 = 0.f;
            float a10 = 0.f, a11 = 0.f, a12 = 0.f, a13 = 0.f;
            float a20 = 0.f, a21 = 0.f, a22 = 0.f, a23 = 0.f;
            float a30 = 0.f, a31 = 0.f, a32 = 0.f, a33 = 0.f;
#pragma unroll
            for (int m = 0; m < 8; ++m) {
                const int o4 = m * 128;      // 32 float4 * 4 floats
                float4 h0 = *(const float4*)(hp0 + o4);
                float4 h1 = *(const float4*)(hp1 + o4);
                float4 h2 = *(const float4*)(hp2 + o4);
                float4 h3 = *(const float4*)(hp3 + o4);
                float4 w0 = *(const float4*)(wp0 + o4);
                float4 w1 = *(const float4*)(wp1 + o4);
                float4 w2 = *(const float4*)(wp2 + o4);
                float4 w3 = *(const float4*)(wp3 + o4);
                D4(a00, h0, w0); D4(a01, h0, w1); D4(a02, h0, w2); D4(a03, h0, w3);
                D4(a10, h1, w0); D4(a11, h1, w1); D4(a12, h1, w2); D4(a13, h1, w3);
                D4(a20, h2, w0); D4(a21, h2, w1); D4(a22, h2, w2); D4(a23, h2, w3);
                D4(a30, h3, w0); D4(a31, h3, w1); D4(a32, h3, w2); D4(a33, h3, w3);
            }
            __syncthreads();   // all dot reads of hyl done -> safe to alias

            // ---- write K-partials: part[o*33 + ks], o = (tb*4+i)*16 + tc*4+j
            pw[ 0 * 33] = a00; pw[ 1 * 33] = a01; pw[ 2 * 33] = a02; pw[ 3 * 33] = a03;
            pw[16 * 33] = a10; pw[17 * 33] = a11; pw[18 * 33] = a12; pw[19 * 33] = a13;
            pw[32 * 33] = a20; pw[33 * 33] = a21; pw[34 * 33] = a22; pw[35 * 33] = a23;
            pw[48 * 33] = a30; pw[49 * 33] = a31; pw[50 * 33] = a32; pw[51 * 33] = a33;
            __syncthreads();

            // ---- combine 32 K-partials for this thread's output ----
            if (tid < 128) {
                const float* pr = part + r * 33;
                float s0 = 0.f, s1 = 0.f, s2 = 0.f, s3 = 0.f;
#pragma unroll
                for (int k = 0; k < 32; k += 4) {
                    s0 += pr[k + 0]; s1 += pr[k + 1];
                    s2 += pr[k + 2]; s3 += pr[k + 3];
                }
                acc = (s0 + s1) + (s2 + s3);
            }
        }

        if (tid < 128) {
            float spike = (u > 0.5f) ? 1.0f : 0.0f;
            u = (spike == 1.0f) ? 0.0f : u;
            u = u * UDEC;
            float drive = tanhf(acc + pre_v);
            hz = hz + DTc * (drive - g * hy - (e * (hz * HARM) + u * SPIK));
            hy = hy + DTc * hz;
            const long long o = (long long)b * TH + (long long)t * Hn + h;
            // hy is the cross-block broadcast value: store to coherent point
            __hip_atomic_store(&hy_o[o], hy,
                               __ATOMIC_RELAXED, __HIP_MEMORY_SCOPE_AGENT);
            hz_o[o] = hz;
            u_o[o]  = u;
            sp_o[o] = spike;
        }

        // ---- per-b-group barrier (64 blocks), monotonic counter ----
        if (t < Tn - 1) {
            __syncthreads();   // drains vmcnt -> sc1 hy stores are at L3
            if (tid == 0) {
                __hip_atomic_fetch_add(ctr, 1u,
                                       __ATOMIC_RELAXED, __HIP_MEMORY_SCOPE_AGENT);
                const unsigned target = 64u * (unsigned)(t + 1);
                while (__hip_atomic_load(ctr, __ATOMIC_RELAXED,
                                         __HIP_MEMORY_SCOPE_AGENT) < target)
                    __builtin_amdgcn_s_sleep(1);
            }
            __syncthreads();
        }
    }
#undef D4
}

// ---------------------------------------------------------------------------
extern "C" void kernel_launch(void* const* d_in, const int* in_sizes, int n_in,
                              void* d_out, int out_size, void* d_ws, size_t ws_size,
                              hipStream_t stream) {
    const float* x    = (const float*)d_in[0];
    const float* x2h  = (const float*)d_in[1];
    const float* h2h  = (const float*)d_in[2];
    const float* gam  = (const float*)d_in[3];
    const float* eps  = (const float*)d_in[4];
    const float* bias = (const float*)d_in[5];
    float* out = (float*)d_out;
    float* pre = out + 2 * BTH;      // park pre in the u output slot

    init_ctr<<<1, 64, 0, stream>>>();
    pre_gemm<<<dim3(16, 256), dim3(256), 0, stream>>>(x, x2h, bias, pre);

    const unsigned smem = (24 * 1028) * sizeof(float);   // 98688 B
    (void)hipFuncSetAttribute((const void*)ron_loop,
                              hipFuncAttributeMaxDynamicSharedMemorySize,
                              (int)smem);
    void* args[] = {(void*)&h2h, (void*)&gam, (void*)&eps, (void*)&out};
    (void)hipLaunchCooperativeKernel((void*)ron_loop, dim3(256), dim3(256),
                                     args, smem, stream);
}

// Round 4
// 2287.124 us; speedup vs baseline: 1.4593x; 1.1180x over previous
//
#include <hip/hip_runtime.h>
#include <cmath>

constexpr int  Bn  = 32, Tn = 512, NIn = 128, Hn = 1024;
constexpr long long TH  = (long long)Tn * Hn;    // 524288
constexpr long long BTH = (long long)Bn * TH;    // 16777216
constexpr float DTc  = 0.042f;
constexpr float UDEC = 1.0f - 1.0f * 1.0f * DTc; // R*C*dt leak
constexpr float HARM = 512.0f;                   // n_hid * p
constexpr float SPIK = 512.0f;                   // n_hid - harmonic

// Per-(b-group, writer-block) step tags, one 64B cacheline each.
// Writer (bg,hg) publishes tag = t+1 after its hy stores are drained.
__device__ unsigned g_tag[4 * 64 * 16];

__global__ void init_tag() {
    int i = threadIdx.x;             // 256 threads, one line each
    __hip_atomic_store(&g_tag[i * 16], 0u,
                       __ATOMIC_RELAXED, __HIP_MEMORY_SCOPE_AGENT);
}

// ---------------------------------------------------------------------------
// pre[row, col] = x[row, :] @ x2h[:, col] + bias[col]  (unchanged, verified)
// ---------------------------------------------------------------------------
__global__ __launch_bounds__(256) void pre_gemm(const float* __restrict__ x,
                                                const float* __restrict__ x2h,
                                                const float* __restrict__ bias,
                                                float* __restrict__ pre) {
    __shared__ float xs[64 * 128];   // [row][k]
    __shared__ float ws[128 * 64];   // [k][col]
    const int tid = threadIdx.x;
    const int rb  = blockIdx.y * 64;
    const int cb  = blockIdx.x * 64;

#pragma unroll
    for (int i = 0; i < 8; ++i) {
        int idx = i * 1024 + tid * 4;
        int r = idx >> 7, k = idx & 127;
        *(float4*)(&xs[r * 128 + k]) =
            *(const float4*)(&x[(long long)(rb + r) * NIn + k]);
    }
#pragma unroll
    for (int i = 0; i < 8; ++i) {
        int idx = i * 1024 + tid * 4;
        int k = idx >> 6, c = idx & 63;
        *(float4*)(&ws[k * 64 + c]) =
            *(const float4*)(&x2h[(long long)k * Hn + cb + c]);
    }
    __syncthreads();

    const int tx = tid & 15, ty = tid >> 4;
    const int r0 = ty * 4, c0 = tx * 4;
    float acc[4][4] = {};
#pragma unroll 4
    for (int k = 0; k < 128; ++k) {
        float4 bv = *(const float4*)(&ws[k * 64 + c0]);
        float a0 = xs[(r0 + 0) * 128 + k];
        float a1 = xs[(r0 + 1) * 128 + k];
        float a2 = xs[(r0 + 2) * 128 + k];
        float a3 = xs[(r0 + 3) * 128 + k];
        acc[0][0] += a0 * bv.x; acc[0][1] += a0 * bv.y; acc[0][2] += a0 * bv.z; acc[0][3] += a0 * bv.w;
        acc[1][0] += a1 * bv.x; acc[1][1] += a1 * bv.y; acc[1][2] += a1 * bv.z; acc[1][3] += a1 * bv.w;
        acc[2][0] += a2 * bv.x; acc[2][1] += a2 * bv.y; acc[2][2] += a2 * bv.z; acc[2][3] += a2 * bv.w;
        acc[3][0] += a3 * bv.x; acc[3][1] += a3 * bv.y; acc[3][2] += a3 * bv.z; acc[3][3] += a3 * bv.w;
    }
    float4 bb = *(const float4*)(&bias[cb + c0]);
#pragma unroll
    for (int i = 0; i < 4; ++i) {
        float4 o;
        o.x = acc[i][0] + bb.x; o.y = acc[i][1] + bb.y;
        o.z = acc[i][2] + bb.z; o.w = acc[i][3] + bb.w;
        *(float4*)(&pre[(long long)(rb + r0 + i) * Hn + cb + c0]) = o;
    }
}

// ---------------------------------------------------------------------------
// Persistent recurrence kernel. 256 blocks = 4 b-groups x 64 h-groups.
// R5 (resubmit, poll softened with s_sleep):
//  (1) tag-array barrier: per-writer release tag + 64-lane __ballot poll
//      replaces the 64-way serialized same-address atomic counter.
//  (2) h2h weights live in registers (float4 W[4][8] per thread, copied once
//      from the staged LDS slice) -> dot LDS traffic halves again.
//  (3) partial scratch moved onto the dead wt region; hyl un-aliased ->
//      one __syncthreads removed per step.
// ---------------------------------------------------------------------------
__global__ __launch_bounds__(256, 1) void ron_loop(const float* __restrict__ h2h,
                                                   const float* __restrict__ gam,
                                                   const float* __restrict__ eps,
                                                   float* __restrict__ out) {
    extern __shared__ float sm[];
    float* hyl  = sm;                // 8 * 1028 floats (staging)
    float* wt   = sm + 8 * 1028;     // 16 * 1028 floats (weights, then scratch)
    float* part = wt;                // alias: 128 outputs * 33 floats (4224)

    const int tid = threadIdx.x;
    const int bx  = blockIdx.x;
    const int hg  = bx & 63;         // 64 h-groups
    const int bg  = bx >> 6;         // 4 b-groups
    const int c0  = hg * 16;
    const int b0  = bg * 8;
    unsigned* mytag   = &g_tag[(bg * 64 + hg) * 16];
    unsigned* tagbase = &g_tag[bg * 64 * 16];

    float* hy_o = out;
    float* hz_o = out + BTH;
    float* u_o  = out + 2 * BTH;     // holds pre until overwritten by u
    float* sp_o = out + 3 * BTH;

    // Stage transposed h2h slice. Coalesced global reads.
    for (int idx = tid; idx < 16 * 1024; idx += 256) {
        int cc2 = idx & 15, k = idx >> 4;
        wt[cc2 * 1028 + k] = h2h[(long long)k * Hn + c0 + cc2];
    }
    __syncthreads();

    // ---- dot decomposition: 8 tiles (2 batch-quads x 4 col-quads) x 32 K-chunks
    const int ks   = tid & 31;       // K-split lane: float4 index ks + 32*m
    const int tile = tid >> 5;       // 0..7
    const int tb   = tile >> 2;      // 0..1  batch quad (rows tb*4 .. tb*4+3)
    const int tc   = tile & 3;       // 0..3  col quad  (cols tc*4 .. tc*4+3)

    // Copy this thread's weights into registers: 4 cols x 8 K-chunks.
    float4 W[4][8];
#pragma unroll
    for (int j = 0; j < 4; ++j)
#pragma unroll
        for (int m = 0; m < 8; ++m)
            W[j][m] = *(const float4*)(wt + (tc * 4 + j) * 1028 + (ks + 32 * m) * 4);
    // wt region is dead from here on (reused as 'part' from t=1; each wave's
    // lgkmcnt(0) at the t=0 end-of-step __syncthreads orders the copy-reads
    // before the first part write).

    const float* hp0 = hyl + (tb * 4 + 0) * 1028 + ks * 4;
    const float* hp1 = hp0 + 1028;
    const float* hp2 = hp0 + 2 * 1028;
    const float* hp3 = hp0 + 3 * 1028;
    float* pw = part + (tb * 64 + tc * 4) * 33 + ks;   // o*33 + ks

    // ---- update-phase identity (threads 0..127 own one (b,h) output) ----
    const int r  = tid & 127;
    const int cc = r & 15;
    const int bb = r >> 4;
    const int b  = b0 + bb;
    const int h  = c0 + cc;
    const float g = gam[h];
    const float e = eps[h];
    float hy = 0.0f, hz = 0.0f, u = 0.0f;

#define D4(dst, hv, wv)                                         \
    dst = fmaf(hv.x, wv.x, dst); dst = fmaf(hv.y, wv.y, dst);   \
    dst = fmaf(hv.z, wv.z, dst); dst = fmaf(hv.w, wv.w, dst)

    for (int t = 0; t < Tn; ++t) {
        // prefetch pre (HBM, ~900 cyc) first: retires during staging+dot
        float pre_v = 0.0f;
        if (tid < 128)
            pre_v = u_o[(long long)b * TH + (long long)t * Hn + h];

        float acc = 0.0f;
        if (t > 0) {
            // ---- stage previous hy rows: 32 L3 loads ALL in flight ----
            const long long base = (long long)b0 * TH + (long long)(t - 1) * Hn + tid;
            float v[32];
#pragma unroll
            for (int i = 0; i < 32; ++i) {
                v[i] = __hip_atomic_load(
                    &hy_o[base + (long long)(i >> 2) * TH + (i & 3) * 256],
                    __ATOMIC_RELAXED, __HIP_MEMORY_SCOPE_AGENT);
            }
#pragma unroll
            for (int i = 0; i < 32; ++i)
                hyl[(i >> 2) * 1028 + (i & 3) * 256 + tid] = v[i];
            __syncthreads();

            // ---- register-tiled dot: 4x4 outputs, K=32 chunks, weights in regs
            float a00 = 0.f, a01 = 0.f, a02 = 0.f, a03 = 0.f;
            float a10 = 0.f, a11 = 0.f, a12 = 0.f, a13 = 0.f;
            float a20 = 0.f, a21 = 0.f, a22 = 0.f, a23 = 0.f;
            float a30 = 0.f, a31 = 0.f, a32 = 0.f, a33 = 0.f;
#pragma unroll
            for (int m = 0; m < 8; ++m) {
                const int o4 = m * 128;      // 32 float4 * 4 floats
                float4 h0 = *(const float4*)(hp0 + o4);
                float4 h1 = *(const float4*)(hp1 + o4);
                float4 h2 = *(const float4*)(hp2 + o4);
                float4 h3 = *(const float4*)(hp3 + o4);
                D4(a00, h0, W[0][m]); D4(a01, h0, W[1][m]); D4(a02, h0, W[2][m]); D4(a03, h0, W[3][m]);
                D4(a10, h1, W[0][m]); D4(a11, h1, W[1][m]); D4(a12, h1, W[2][m]); D4(a13, h1, W[3][m]);
                D4(a20, h2, W[0][m]); D4(a21, h2, W[1][m]); D4(a22, h2, W[2][m]); D4(a23, h2, W[3][m]);
                D4(a30, h3, W[0][m]); D4(a31, h3, W[1][m]); D4(a32, h3, W[2][m]); D4(a33, h3, W[3][m]);
            }

            // ---- write K-partials: part[o*33 + ks], o = (tb*4+i)*16 + tc*4+j
            pw[ 0 * 33] = a00; pw[ 1 * 33] = a01; pw[ 2 * 33] = a02; pw[ 3 * 33] = a03;
            pw[16 * 33] = a10; pw[17 * 33] = a11; pw[18 * 33] = a12; pw[19 * 33] = a13;
            pw[32 * 33] = a20; pw[33 * 33] = a21; pw[34 * 33] = a22; pw[35 * 33] = a23;
            pw[48 * 33] = a30; pw[49 * 33] = a31; pw[50 * 33] = a32; pw[51 * 33] = a33;
            __syncthreads();

            // ---- combine 32 K-partials for this thread's output ----
            if (tid < 128) {
                const float* pr = part + r * 33;
                float s0 = 0.f, s1 = 0.f, s2 = 0.f, s3 = 0.f;
#pragma unroll
                for (int k = 0; k < 32; k += 4) {
                    s0 += pr[k + 0]; s1 += pr[k + 1];
                    s2 += pr[k + 2]; s3 += pr[k + 3];
                }
                acc = (s0 + s1) + (s2 + s3);
            }
        }

        if (tid < 128) {
            float spike = (u > 0.5f) ? 1.0f : 0.0f;
            u = (spike == 1.0f) ? 0.0f : u;
            u = u * UDEC;
            float drive = tanhf(acc + pre_v);
            hz = hz + DTc * (drive - g * hy - (e * (hz * HARM) + u * SPIK));
            hy = hy + DTc * hz;
            const long long o = (long long)b * TH + (long long)t * Hn + h;
            // hy is the cross-block broadcast value: store to coherent point
            __hip_atomic_store(&hy_o[o], hy,
                               __ATOMIC_RELAXED, __HIP_MEMORY_SCOPE_AGENT);
            hz_o[o] = hz;
            u_o[o]  = u;
            sp_o[o] = spike;
        }

        // ---- per-b-group barrier (64 blocks), tag publish + 64-lane poll ----
        if (t < Tn - 1) {
            __syncthreads();   // drains vmcnt -> sc1 hy stores are at L3
            if (tid == 0)
                __hip_atomic_store(mytag, (unsigned)(t + 1),
                                   __ATOMIC_RELAXED, __HIP_MEMORY_SCOPE_AGENT);
            if (tid < 64) {
                const unsigned target = (unsigned)(t + 1);
                for (;;) {
                    unsigned v = __hip_atomic_load(&tagbase[tid * 16],
                                                   __ATOMIC_RELAXED,
                                                   __HIP_MEMORY_SCOPE_AGENT);
                    if (__ballot(v < target) == 0ull) break;
                    __builtin_amdgcn_s_sleep(1);
                }
            }
            __syncthreads();
        }
    }
#undef D4
}

// ---------------------------------------------------------------------------
extern "C" void kernel_launch(void* const* d_in, const int* in_sizes, int n_in,
                              void* d_out, int out_size, void* d_ws, size_t ws_size,
                              hipStream_t stream) {
    const float* x    = (const float*)d_in[0];
    const float* x2h  = (const float*)d_in[1];
    const float* h2h  = (const float*)d_in[2];
    const float* gam  = (const float*)d_in[3];
    const float* eps  = (const float*)d_in[4];
    const float* bias = (const float*)d_in[5];
    float* out = (float*)d_out;
    float* pre = out + 2 * BTH;      // park pre in the u output slot

    init_tag<<<1, 256, 0, stream>>>();
    pre_gemm<<<dim3(16, 256), dim3(256), 0, stream>>>(x, x2h, bias, pre);

    const unsigned smem = (24 * 1028) * sizeof(float);   // 98688 B
    (void)hipFuncSetAttribute((const void*)ron_loop,
                              hipFuncAttributeMaxDynamicSharedMemorySize,
                              (int)smem);
    void* args[] = {(void*)&h2h, (void*)&gam, (void*)&eps, (void*)&out};
    (void)hipLaunchCooperativeKernel((void*)ron_loop, dim3(256), dim3(256),
                                     args, smem, stream);
}

// Round 5
// 1837.182 us; speedup vs baseline: 1.8167x; 1.2449x over previous
//
#include <hip/hip_runtime.h>
#include <cmath>

constexpr int  Bn  = 32, Tn = 512, NIn = 128, Hn = 1024;
constexpr long long TH  = (long long)Tn * Hn;    // 524288
constexpr long long BTH = (long long)Bn * TH;    // 16777216
constexpr float DTc  = 0.042f;
constexpr float UDEC = 1.0f - 1.0f * 1.0f * DTc; // R*C*dt leak
constexpr float HARM = 512.0f;                   // n_hid * p
constexpr float SPIK = 512.0f;                   // n_hid - harmonic

// Per-(b-group, writer-block) step tags, one 64B cacheline each.
// 8 b-groups x 32 writers. Writer publishes tag = t+1 after hy stores drain.
__device__ unsigned g_tag[8 * 32 * 16];

__global__ void init_tag() {
    int i = threadIdx.x;             // 256 threads, one line each
    __hip_atomic_store(&g_tag[i * 16], 0u,
                       __ATOMIC_RELAXED, __HIP_MEMORY_SCOPE_AGENT);
}

// ---------------------------------------------------------------------------
// pre[row, col] = x[row, :] @ x2h[:, col] + bias[col]  (unchanged, verified)
// ---------------------------------------------------------------------------
__global__ __launch_bounds__(256) void pre_gemm(const float* __restrict__ x,
                                                const float* __restrict__ x2h,
                                                const float* __restrict__ bias,
                                                float* __restrict__ pre) {
    __shared__ float xs[64 * 128];   // [row][k]
    __shared__ float ws[128 * 64];   // [k][col]
    const int tid = threadIdx.x;
    const int rb  = blockIdx.y * 64;
    const int cb  = blockIdx.x * 64;

#pragma unroll
    for (int i = 0; i < 8; ++i) {
        int idx = i * 1024 + tid * 4;
        int r = idx >> 7, k = idx & 127;
        *(float4*)(&xs[r * 128 + k]) =
            *(const float4*)(&x[(long long)(rb + r) * NIn + k]);
    }
#pragma unroll
    for (int i = 0; i < 8; ++i) {
        int idx = i * 1024 + tid * 4;
        int k = idx >> 6, c = idx & 63;
        *(float4*)(&ws[k * 64 + c]) =
            *(const float4*)(&x2h[(long long)k * Hn + cb + c]);
    }
    __syncthreads();

    const int tx = tid & 15, ty = tid >> 4;
    const int r0 = ty * 4, c0 = tx * 4;
    float acc[4][4] = {};
#pragma unroll 4
    for (int k = 0; k < 128; ++k) {
        float4 bv = *(const float4*)(&ws[k * 64 + c0]);
        float a0 = xs[(r0 + 0) * 128 + k];
        float a1 = xs[(r0 + 1) * 128 + k];
        float a2 = xs[(r0 + 2) * 128 + k];
        float a3 = xs[(r0 + 3) * 128 + k];
        acc[0][0] += a0 * bv.x; acc[0][1] += a0 * bv.y; acc[0][2] += a0 * bv.z; acc[0][3] += a0 * bv.w;
        acc[1][0] += a1 * bv.x; acc[1][1] += a1 * bv.y; acc[1][2] += a1 * bv.z; acc[1][3] += a1 * bv.w;
        acc[2][0] += a2 * bv.x; acc[2][1] += a2 * bv.y; acc[2][2] += a2 * bv.z; acc[2][3] += a2 * bv.w;
        acc[3][0] += a3 * bv.x; acc[3][1] += a3 * bv.y; acc[3][2] += a3 * bv.z; acc[3][3] += a3 * bv.w;
    }
    float4 bb = *(const float4*)(&bias[cb + c0]);
#pragma unroll
    for (int i = 0; i < 4; ++i) {
        float4 o;
        o.x = acc[i][0] + bb.x; o.y = acc[i][1] + bb.y;
        o.z = acc[i][2] + bb.z; o.w = acc[i][3] + bb.w;
        *(float4*)(&pre[(long long)(rb + r0 + i) * Hn + cb + c0]) = o;
    }
}

// ---------------------------------------------------------------------------
// Persistent recurrence kernel. 256 blocks = 8 b-groups x 32 h-groups.
// R6 changes:
//  (1) XCD-local exchange: bg = blockIdx.x & 7, so each b-group's 32 blocks
//      land on one XCD under round-robin dispatch; hy + tag lines stay in
//      that XCD's L2 (~200-300 cyc round trips instead of ~900 via L3).
//      Correctness does not depend on the mapping (device-scope atomics).
//  (2) 4 batches x 32 h per block; same per-thread work (512 MAC, W[4][8]
//      in regs over a K=32-chunk x 4-col slice); staging halves to 4 rows.
//  (3) hy store -> drain -> publish reordered before hz/u/sp stores, which
//      now overlap the tag poll.
// ---------------------------------------------------------------------------
__global__ __launch_bounds__(256, 1) void ron_loop(const float* __restrict__ h2h,
                                                   const float* __restrict__ gam,
                                                   const float* __restrict__ eps,
                                                   float* __restrict__ out) {
    extern __shared__ float sm[];
    float* hyl  = sm;                // 4 * 1028 floats (staging)
    float* wt   = sm + 4 * 1028;     // 32 * 1028 floats (weights, then scratch)
    float* part = wt;                // alias: 128 outputs * 33 floats (4224)

    const int tid = threadIdx.x;
    const int bx  = blockIdx.x;
    const int bg  = bx & 7;          // XCD id under round-robin dispatch
    const int hg  = bx >> 3;         // 32 h-groups
    const int c0  = hg * 32;
    const int b0  = bg * 4;
    unsigned* mytag   = &g_tag[(bg * 32 + hg) * 16];
    unsigned* tagbase = &g_tag[bg * 32 * 16];

    float* hy_o = out;
    float* hz_o = out + BTH;
    float* u_o  = out + 2 * BTH;     // holds pre until overwritten by u
    float* sp_o = out + 3 * BTH;

    // Stage transposed h2h slice (once): wt[col][k], col 0..31.
    for (int idx = tid; idx < 32 * 1024; idx += 256) {
        int cc2 = idx & 31, k = idx >> 5;
        wt[cc2 * 1028 + k] = h2h[(long long)k * Hn + c0 + cc2];
    }
    __syncthreads();

    // ---- dot decomposition: 8 tiles (col-quads... 8*4=32 cols) x 32 K-chunks
    const int ks   = tid & 31;       // K-split lane: float4 index ks + 32*m
    const int tile = tid >> 5;       // 0..7: cols tile*4 .. tile*4+3

    // Copy this thread's weights into registers: 4 cols x 8 K-chunks.
    float4 W[4][8];
#pragma unroll
    for (int j = 0; j < 4; ++j)
#pragma unroll
        for (int m = 0; m < 8; ++m)
            W[j][m] = *(const float4*)(wt + (tile * 4 + j) * 1028 + (ks + 32 * m) * 4);
    // wt region is dead from here on; reused as 'part' from t=1 (ordered by
    // the t=0 end-of-step __syncthreads).

    const float* hp0 = hyl + 0 * 1028 + ks * 4;   // batch rows 0..3
    const float* hp1 = hp0 + 1028;
    const float* hp2 = hp0 + 2 * 1028;
    const float* hp3 = hp0 + 3 * 1028;
    float* pw = part + (tile * 4) * 33 + ks;      // + (bi*32 + j)*33

    // ---- update-phase identity (threads 0..127 own one (b,h) output) ----
    const int r  = tid & 127;
    const int cc = r & 31;
    const int bb = r >> 5;
    const int b  = b0 + bb;
    const int h  = c0 + cc;
    const float g = gam[h];
    const float e = eps[h];
    float hy = 0.0f, hz = 0.0f, u = 0.0f;

#define D4(dst, hv, wv)                                         \
    dst = fmaf(hv.x, wv.x, dst); dst = fmaf(hv.y, wv.y, dst);   \
    dst = fmaf(hv.z, wv.z, dst); dst = fmaf(hv.w, wv.w, dst)

    for (int t = 0; t < Tn; ++t) {
        // prefetch pre (HBM, ~900 cyc): retires during staging+dot
        float pre_v = 0.0f;
        if (tid < 128)
            pre_v = u_o[(long long)b * TH + (long long)t * Hn + h];

        float acc = 0.0f;
        if (t > 0) {
            // ---- stage previous hy rows (4 x 1024): 16 loads in flight ----
            const long long base = (long long)b0 * TH + (long long)(t - 1) * Hn + tid;
            float v[16];
#pragma unroll
            for (int i = 0; i < 16; ++i) {
                v[i] = __hip_atomic_load(
                    &hy_o[base + (long long)(i >> 2) * TH + (i & 3) * 256],
                    __ATOMIC_RELAXED, __HIP_MEMORY_SCOPE_AGENT);
            }
#pragma unroll
            for (int i = 0; i < 16; ++i)
                hyl[(i >> 2) * 1028 + (i & 3) * 256 + tid] = v[i];
            __syncthreads();

            // ---- register-tiled dot: 4 batches x 4 cols, K=32 chunk ----
            float a00 = 0.f, a01 = 0.f, a02 = 0.f, a03 = 0.f;
            float a10 = 0.f, a11 = 0.f, a12 = 0.f, a13 = 0.f;
            float a20 = 0.f, a21 = 0.f, a22 = 0.f, a23 = 0.f;
            float a30 = 0.f, a31 = 0.f, a32 = 0.f, a33 = 0.f;
#pragma unroll
            for (int m = 0; m < 8; ++m) {
                const int o4 = m * 128;      // 32 float4 * 4 floats
                float4 h0 = *(const float4*)(hp0 + o4);
                float4 h1 = *(const float4*)(hp1 + o4);
                float4 h2 = *(const float4*)(hp2 + o4);
                float4 h3 = *(const float4*)(hp3 + o4);
                D4(a00, h0, W[0][m]); D4(a01, h0, W[1][m]); D4(a02, h0, W[2][m]); D4(a03, h0, W[3][m]);
                D4(a10, h1, W[0][m]); D4(a11, h1, W[1][m]); D4(a12, h1, W[2][m]); D4(a13, h1, W[3][m]);
                D4(a20, h2, W[0][m]); D4(a21, h2, W[1][m]); D4(a22, h2, W[2][m]); D4(a23, h2, W[3][m]);
                D4(a30, h3, W[0][m]); D4(a31, h3, W[1][m]); D4(a32, h3, W[2][m]); D4(a33, h3, W[3][m]);
            }

            // ---- write K-partials: part[(bi*32 + tile*4 + j)*33 + ks] ----
            pw[(0 * 32 + 0) * 33] = a00; pw[(0 * 32 + 1) * 33] = a01;
            pw[(0 * 32 + 2) * 33] = a02; pw[(0 * 32 + 3) * 33] = a03;
            pw[(1 * 32 + 0) * 33] = a10; pw[(1 * 32 + 1) * 33] = a11;
            pw[(1 * 32 + 2) * 33] = a12; pw[(1 * 32 + 3) * 33] = a13;
            pw[(2 * 32 + 0) * 33] = a20; pw[(2 * 32 + 1) * 33] = a21;
            pw[(2 * 32 + 2) * 33] = a22; pw[(2 * 32 + 3) * 33] = a23;
            pw[(3 * 32 + 0) * 33] = a30; pw[(3 * 32 + 1) * 33] = a31;
            pw[(3 * 32 + 2) * 33] = a32; pw[(3 * 32 + 3) * 33] = a33;
            __syncthreads();

            // ---- combine 32 K-partials for this thread's output ----
            if (tid < 128) {
                const float* pr = part + r * 33;
                float s0 = 0.f, s1 = 0.f, s2 = 0.f, s3 = 0.f;
#pragma unroll
                for (int k = 0; k < 32; k += 4) {
                    s0 += pr[k + 0]; s1 += pr[k + 1];
                    s2 += pr[k + 2]; s3 += pr[k + 3];
                }
                acc = (s0 + s1) + (s2 + s3);
            }
        }

        float spike = 0.0f;
        long long o = 0;
        if (tid < 128) {
            spike = (u > 0.5f) ? 1.0f : 0.0f;
            u = (spike == 1.0f) ? 0.0f : u;
            u = u * UDEC;
            float drive = tanhf(acc + pre_v);
            hz = hz + DTc * (drive - g * hy - (e * (hz * HARM) + u * SPIK));
            hy = hy + DTc * hz;
            o = (long long)b * TH + (long long)t * Hn + h;
            // hy is the cross-block broadcast value: store to coherent point
            __hip_atomic_store(&hy_o[o], hy,
                               __ATOMIC_RELAXED, __HIP_MEMORY_SCOPE_AGENT);
        }

        if (t < Tn - 1) {
            __syncthreads();   // drains vmcnt -> hy stores at coherent point
            if (tid == 0)
                __hip_atomic_store(mytag, (unsigned)(t + 1),
                                   __ATOMIC_RELAXED, __HIP_MEMORY_SCOPE_AGENT);
        }

        // hz/u/sp stores off the publish critical path; overlap the poll.
        if (tid < 128) {
            hz_o[o] = hz;
            u_o[o]  = u;
            sp_o[o] = spike;
        }

        if (t < Tn - 1) {
            if (tid < 64) {
                const unsigned target = (unsigned)(t + 1);
                const int idx = tid & 31;
                for (;;) {
                    unsigned v = __hip_atomic_load(&tagbase[idx * 16],
                                                   __ATOMIC_RELAXED,
                                                   __HIP_MEMORY_SCOPE_AGENT);
                    if (__ballot(v < target) == 0ull) break;
                    __builtin_amdgcn_s_sleep(1);
                }
            }
            __syncthreads();
        }
    }
#undef D4
}

// ---------------------------------------------------------------------------
extern "C" void kernel_launch(void* const* d_in, const int* in_sizes, int n_in,
                              void* d_out, int out_size, void* d_ws, size_t ws_size,
                              hipStream_t stream) {
    const float* x    = (const float*)d_in[0];
    const float* x2h  = (const float*)d_in[1];
    const float* h2h  = (const float*)d_in[2];
    const float* gam  = (const float*)d_in[3];
    const float* eps  = (const float*)d_in[4];
    const float* bias = (const float*)d_in[5];
    float* out = (float*)d_out;
    float* pre = out + 2 * BTH;      // park pre in the u output slot

    init_tag<<<1, 256, 0, stream>>>();
    pre_gemm<<<dim3(16, 256), dim3(256), 0, stream>>>(x, x2h, bias, pre);

    const unsigned smem = (4 * 1028 + 32 * 1028) * sizeof(float);   // 148032 B
    (void)hipFuncSetAttribute((const void*)ron_loop,
                              hipFuncAttributeMaxDynamicSharedMemorySize,
                              (int)smem);
    void* args[] = {(void*)&h2h, (void*)&gam, (void*)&eps, (void*)&out};
    (void)hipLaunchCooperativeKernel((void*)ron_loop, dim3(256), dim3(256),
                                     args, smem, stream);
}